// Round 14
// baseline (82.507 us; speedup 1.0000x reference)
//
#include <hip/hip_runtime.h>
#include <hip/hip_fp16.h>

// EdgeWeightNorm (norm='both'), EPS = 0.
// out[e] = outdeg[src[e]]^-0.5 * indeg[dst[e]]^-0.5 * w[e]
//
// Journal:
// R1/R2: global fp32 atomics go to the coherence point regardless of scope
//   (~20 G atomics/s) -> never use them for the 12.8M adds.
// R3: multi-pass LDS histograms (fixed-point, ds_add_u32).
// R4/R5: 160KB LDS + u16x2 packing -> 3 passes. R6/R7: random VMEM gathers
//   pinned by per-CU outstanding-miss cap; ILP/NT null.
// R8: prod gathers from LDS-resident f16 norm slices. R9: XCD co-schedule
//   swizzle (FETCH 112->37.5MB). R10: 1-deep hist pipeline (+1-2us).
// R11: reg-staged dbuf prod spilled -> regressed. R12: KMAX=4, 2 blocks/CU
//   TLP prod -> total 68.8us (hist 39 / reduce ~8 / prod ~19).
// R13: 10-bit x3 packing -> P=2: hist improved (<39) but reduce TLP fell
//   100K->41K threads -> reduce ~20us -> total 77.1. Lesson: every phase
//   needs its TLP budget checked, not just its traffic.
// R14: keep 10-bit hist; reduce split per (pass, word, TABLE) -> 82K
//   threads, half the loads per thread -> reduce back to ~9us.

#define N_NODES 100000
#define TWO_N   (2 * N_NODES)
#define THREADS 1024
#define GBLK    1024
#define KMAX    4              // quads per thread in prod (4*1024*512 >= n4)
#define SCALE10     32.0f      // 2^5, 10-bit histogram fields
#define INV_SCALE10 0.03125f   // 2^-5

// ---------------- degree histogram ----------------
// grid = P*C blocks. pass j covers nodes [j*3*binw, (j+1)*3*binw) for BOTH
// tables; LDS = src section [0,binw) | dst section [binw,2*binw), u32 words
// with 3 x 10-bit fields (node f*binw+wd -> word wd, bits 10f..10f+9).
// Overflow-safe: per-chunk per-field sums ~<900 < 1023 (lambda=0.5/chunk).
// swz!=0 requires C%8==0: same-chunk pass-pairs co-resident on one XCD.
__global__ __launch_bounds__(THREADS, 4)
void hist_kernel(const float4* __restrict__ w4,
                 const int4* __restrict__ src4,
                 const int4* __restrict__ dst4,
                 const float* __restrict__ w,
                 const int* __restrict__ src,
                 const int* __restrict__ dst,
                 unsigned* __restrict__ parts,
                 int n4, int n_edges, int P, int C, int binw, int chunk4,
                 int swz)
{
    extern __shared__ unsigned lds[];   // [2*binw]
    int j, c;
    if (swz) {
        const int x = blockIdx.x & 7;
        const int r = blockIdx.x >> 3;
        j = r % P;
        c = x + 8 * (r / P);
    } else {
        j = blockIdx.x / C;
        c = blockIdx.x - j * C;
    }
    const int NRH = 3 * binw;
    const int lo  = j * NRH;
    const unsigned ubinw = (unsigned)binw;
    const unsigned uNRH  = (unsigned)NRH;
    unsigned* __restrict__ ldsd = lds + binw;   // dst section

    for (int k = threadIdx.x; k < 2 * binw; k += THREADS) lds[k] = 0;
    __syncthreads();

    const int beg = c * chunk4;
    const int end = min(n4, beg + chunk4);
    const int t   = threadIdx.x;

#define ENDP(nd, vq, base_)                                                   \
    do {                                                                      \
        unsigned l_ = (unsigned)((nd) - lo);                                  \
        if (l_ < uNRH) {                                                      \
            unsigned f_ = (unsigned)(l_ >= ubinw) + (unsigned)(l_ >= 2u * ubinw); \
            unsigned wd_ = l_ - f_ * ubinw;                                   \
            atomicAdd(&base_[wd_], (vq) << (10u * f_));                       \
        }                                                                     \
    } while (0)

#define QUAD(wv, sv, dv)                                                      \
    do {                                                                      \
        unsigned v0 = (unsigned)((wv).x * SCALE10 + 0.5f);                    \
        unsigned v1 = (unsigned)((wv).y * SCALE10 + 0.5f);                    \
        unsigned v2 = (unsigned)((wv).z * SCALE10 + 0.5f);                    \
        unsigned v3 = (unsigned)((wv).w * SCALE10 + 0.5f);                    \
        ENDP((sv).x, v0, lds);  ENDP((sv).y, v1, lds);                        \
        ENDP((sv).z, v2, lds);  ENDP((sv).w, v3, lds);                        \
        ENDP((dv).x, v0, ldsd); ENDP((dv).y, v1, ldsd);                       \
        ENDP((dv).z, v2, ldsd); ENDP((dv).w, v3, ldsd);                       \
    } while (0)

    // 1-deep software pipeline over groups of 2 quads (6 vec4 loads/group).
    {
        const int total = end - beg;                          // uniform
        const int trips = (total + 2 * THREADS - 1) / (2 * THREADS);
        int i = beg + t;

        float4 wc0, wc1, wn0, wn1;
        int4   sc0, sc1, sn0, sn1, dc0, dc1, dn0, dn1;
        bool   pc0, pc1, pn0, pn1;

        pn0 = i < end;
        pn1 = (i + THREADS) < end;
        if (pn0) { wn0 = w4[i];           sn0 = src4[i];           dn0 = dst4[i]; }
        if (pn1) { wn1 = w4[i + THREADS]; sn1 = src4[i + THREADS]; dn1 = dst4[i + THREADS]; }

        for (int tr = 0; tr < trips; ++tr) {
            wc0 = wn0; sc0 = sn0; dc0 = dn0; pc0 = pn0;
            wc1 = wn1; sc1 = sn1; dc1 = dn1; pc1 = pn1;

            const int ni = i + 2 * THREADS;
            pn0 = (tr + 1 < trips) && (ni < end);
            pn1 = (tr + 1 < trips) && ((ni + THREADS) < end);
            if (pn0) { wn0 = w4[ni];           sn0 = src4[ni];           dn0 = dst4[ni]; }
            if (pn1) { wn1 = w4[ni + THREADS]; sn1 = src4[ni + THREADS]; dn1 = dst4[ni + THREADS]; }

            __builtin_amdgcn_sched_barrier(0);

            if (pc0) QUAD(wc0, sc0, dc0);
            if (pc1) QUAD(wc1, sc1, dc1);
            i = ni;
        }
    }
#undef QUAD

    if (c == C - 1 && threadIdx.x == 0) {        // tail edges (none for E=6.4M)
        for (int e = n4 * 4; e < n_edges; ++e) {
            unsigned v = (unsigned)(w[e] * SCALE10 + 0.5f);
            ENDP(src[e], v, lds);
            ENDP(dst[e], v, ldsd);
        }
    }
#undef ENDP

    __syncthreads();
    unsigned* op = parts + (size_t)(j * C + c) * (2 * binw);
    for (int k = threadIdx.x; k < 2 * binw; k += THREADS)
        __builtin_nontemporal_store(lds[k], op + k);   // bulk dump
}

// --- reduce partials -> f16 norm tables. One thread per (pass, word,
// TABLE-section): 2*P*binw threads (82K) for TLP; unpacks 3 nodes each. ---
__global__ void reduce_rsqrt_kernel(const unsigned* __restrict__ parts,
                                    __half* __restrict__ normh,
                                    int P, int C, int binw)
{
    const int tid = blockIdx.x * blockDim.x + threadIdx.x;
    const int per = P * binw;
    if (tid >= 2 * per) return;
    const int half = tid / per;                        // 0 = src, 1 = dst
    const int r    = tid - half * per;
    const int j    = r / binw;
    const int wd   = r - j * binw;
    const int NRH  = 3 * binw;
    const size_t stride = (size_t)2 * binw;            // words per chunk record
    const unsigned* base = parts + (size_t)j * C * stride + (size_t)half * binw + wd;

    unsigned s0 = 0, s1 = 0, s2 = 0;
    unsigned t0 = 0, t1 = 0, t2 = 0;                   // second accumulator set
    int c = 0;
    for (; c + 1 < C; c += 2) {
        const unsigned va = base[(size_t)c * stride];
        const unsigned vb = base[(size_t)(c + 1) * stride];
        s0 += va & 1023u; s1 += (va >> 10) & 1023u; s2 += (va >> 20) & 1023u;
        t0 += vb & 1023u; t1 += (vb >> 10) & 1023u; t2 += (vb >> 20) & 1023u;
    }
    for (; c < C; ++c) {
        const unsigned va = base[(size_t)c * stride];
        s0 += va & 1023u; s1 += (va >> 10) & 1023u; s2 += (va >> 20) & 1023u;
    }
    s0 += t0; s1 += t1; s2 += t2;

    const int n0 = j * NRH + wd;
    const int n1 = n0 + binw;
    const int n2 = n0 + 2 * binw;
    __half* tab = normh + half * N_NODES;
    // deg==0 -> inf matches 0**-0.5 (never gathered: an edge implies deg>0)
    if (n0 < N_NODES) tab[n0] = __float2half(1.0f / sqrtf((float)s0 * INV_SCALE10));
    if (n1 < N_NODES) tab[n1] = __float2half(1.0f / sqrtf((float)s1 * INV_SCALE10));
    if (n2 < N_NODES) tab[n2] = __float2half(1.0f / sqrtf((float)s2 * INV_SCALE10));
}

// ---------------- fallback path (tiny ws): device atomics ----------------
__global__ void degree_atomic_kernel(const float* __restrict__ w,
                                     const int* __restrict__ src,
                                     const int* __restrict__ dst,
                                     float* __restrict__ deg,
                                     int n_edges)
{
    int i = blockIdx.x * blockDim.x + threadIdx.x;
    int stride = gridDim.x * blockDim.x;
    for (; i < n_edges; i += stride) {
        float wi = w[i];
        atomicAdd(&deg[src[i]], wi);
        atomicAdd(&deg[N_NODES + dst[i]], wi);
    }
}

__global__ void rsqrt_half_kernel(const float* __restrict__ deg,
                                  __half* __restrict__ normh, int n)
{
    int i = blockIdx.x * blockDim.x + threadIdx.x;
    if (i < n) normh[i] = __float2half(1.0f / sqrtf(deg[i]));
}

// ------- output pass (R12 structure): edges in regs (KMAX=4, no spill);
// single 80KB interleaved slice (srcn|dstn, NR nodes); 2 blocks/CU
// co-resident so one block's fill overlaps the other's gather. -------
__global__ __launch_bounds__(GBLK, 8)
void prod_kernel(const float4* __restrict__ w4,
                 const int4* __restrict__ src4,
                 const int4* __restrict__ dst4,
                 const __half* __restrict__ srcn_h,
                 const __half* __restrict__ dstn_h,
                 float4* __restrict__ out4,
                 int n4, int n_edges, int qpb, int NR,
                 const float* __restrict__ w,
                 const int* __restrict__ src,
                 const int* __restrict__ dst,
                 float* __restrict__ out)
{
    extern __shared__ __half lh[];     // [2*NR]: srcn slice | dstn slice
    const int q0   = blockIdx.x * qpb;
    const int qend = min(n4, q0 + qpb);
    const int t    = threadIdx.x;
    const int passes  = (N_NODES + NR - 1) / NR;
    const int half_u4 = NR >> 3;       // uint4 per table slice
    const int tot_u4  = NR >> 2;       // uint4 per (both-tables) slice

    float4 pr[KMAX];
    int4   sv[KMAX], dv[KMAX];
    bool   val[KMAX];
#pragma unroll
    for (int k = 0; k < KMAX; ++k) {
        const int q = q0 + k * GBLK + t;
        val[k] = q < qend;
        if (val[k]) {
            pr[k] = w4[q];             // product accumulator starts at w
            sv[k] = src4[q];
            dv[k] = dst4[q];
        }
    }

    for (int p = 0; p < passes; ++p) {
        if (p > 0) __syncthreads();            // prev gathers done before overwrite
        {
            const int base_ = p * NR;
            const uint4* gs = (const uint4*)(srcn_h + base_);
            const uint4* gd = (const uint4*)(dstn_h + base_);
            uint4* lb = (uint4*)lh;
            for (int idx = t; idx < tot_u4; idx += GBLK)
                lb[idx] = (idx < half_u4) ? gs[idx] : gd[idx - half_u4];
        }
        __syncthreads();

        const int lo = p * NR;
        const unsigned lenU = (unsigned)min(NR, N_NODES - lo);
        const __half* ls  = lh;
        const __half* ldt = lh + NR;
#pragma unroll
        for (int k = 0; k < KMAX; ++k) {
            if (!val[k]) continue;
            unsigned a;
            a = (unsigned)(sv[k].x - lo); if (a < lenU) pr[k].x *= __half2float(ls[a]);
            a = (unsigned)(sv[k].y - lo); if (a < lenU) pr[k].y *= __half2float(ls[a]);
            a = (unsigned)(sv[k].z - lo); if (a < lenU) pr[k].z *= __half2float(ls[a]);
            a = (unsigned)(sv[k].w - lo); if (a < lenU) pr[k].w *= __half2float(ls[a]);
            a = (unsigned)(dv[k].x - lo); if (a < lenU) pr[k].x *= __half2float(ldt[a]);
            a = (unsigned)(dv[k].y - lo); if (a < lenU) pr[k].y *= __half2float(ldt[a]);
            a = (unsigned)(dv[k].z - lo); if (a < lenU) pr[k].z *= __half2float(ldt[a]);
            a = (unsigned)(dv[k].w - lo); if (a < lenU) pr[k].w *= __half2float(ldt[a]);
        }
    }

#pragma unroll
    for (int k = 0; k < KMAX; ++k) {
        const int q = q0 + k * GBLK + t;
        if (val[k]) out4[q] = pr[k];
    }

    if (blockIdx.x == 0 && t == 0) {   // tail edges (none for E=6.4M)
        for (int e = n4 * 4; e < n_edges; ++e)
            out[e] = __half2float(srcn_h[src[e]]) * __half2float(dstn_h[dst[e]]) * w[e];
    }
}

extern "C" void kernel_launch(void* const* d_in, const int* in_sizes, int n_in,
                              void* d_out, int out_size, void* d_ws, size_t ws_size,
                              hipStream_t stream)
{
    const float* w   = (const float*)d_in[0];
    const int*   src = (const int*)d_in[1];
    const int*   dst = (const int*)d_in[2];
    const int E  = in_sizes[0];
    const int n4 = E >> 2;
    float* out = (float*)d_out;

    // ws layout: [0, 1MB) f16 norm tables (srcn | dstn; slack for OOB-safe
    // vectorized slice fills); [1MB, ...) scratch
    __half* normh = (__half*)d_ws;
    char* scratch = (char*)d_ws + (1 << 20);
    unsigned* parts = (unsigned*)scratch;
    float* degf = (float*)scratch;               // fallback f32 degrees
    size_t avail_u = (ws_size > (1u << 20)) ? (ws_size - (1 << 20)) / 4 : 0;

    // hist wants max LDS (fewest passes): 160KB -> 128 -> 80 -> 64KB.
    const int cands[3] = {163840, 131072, 81920};
    int lds_hist = 65536;
    for (int tC = 0; tC < 3; ++tC)
        if (hipFuncSetAttribute((const void*)hist_kernel,
                                hipFuncAttributeMaxDynamicSharedMemorySize,
                                cands[tC]) == hipSuccess) { lds_hist = cands[tC]; break; }
    // prod wants 80KB (2 blocks/CU co-residency); fallback 64KB.
    int lds_prod = 65536;
    if (hipFuncSetAttribute((const void*)prod_kernel,
                            hipFuncAttributeMaxDynamicSharedMemorySize,
                            81920) == hipSuccess)
        lds_prod = 81920;

    const int binw = lds_hist / 8;               // u32 words per table section
    const int NRH  = 3 * binw;                   // nodes per pass (10-bit x 3)
    const int P = (N_NODES + NRH - 1) / NRH;     // 2 at 160KB

    const int blk_per_cu = 163840 / lds_hist;
    int C = (256 * blk_per_cu) / P;              // 128 at 160KB
    const size_t per_chunk_u = (size_t)P * (size_t)(2 * binw);
    if (avail_u < per_chunk_u) C = 0;
    else {
        int cmax = (int)(avail_u / per_chunk_u);
        if (C > cmax) C = cmax;
    }

    // XCD co-scheduling swizzle needs C % 8 == 0.
    int swz = 0;
    if (C >= 8) { C &= ~7; swz = 1; }

    if (C >= 1) {
        const int chunk4 = (n4 + C - 1) / C;
        hist_kernel<<<P * C, THREADS, (size_t)lds_hist, stream>>>(
            (const float4*)w, (const int4*)src, (const int4*)dst,
            w, src, dst, parts, n4, E, P, C, binw, chunk4, swz);
        const int rthreads = 2 * P * binw;       // per (pass, word, table)
        reduce_rsqrt_kernel<<<(rthreads + 255) / 256, 256, 0, stream>>>(
            parts, normh, P, C, binw);
    } else {
        hipMemsetAsync(degf, 0, (size_t)TWO_N * sizeof(float), stream);
        degree_atomic_kernel<<<2048, 256, 0, stream>>>(w, src, dst, degf, E);
        rsqrt_half_kernel<<<(TWO_N + 255) / 256, 256, 0, stream>>>(degf, normh, TWO_N);
    }

    {
        // NR nodes per slice; LDS = 2 tables x NR x 2B = 4*NR bytes.
        const int NR = lds_prod / 4;             // 20480 at 80KB
        const int maxq = KMAX * GBLK;            // 4096 quads/block capacity
        int C2 = (n4 + maxq - 1) / maxq;
        if (C2 < 512) C2 = 512;                  // 2 blocks/CU on all CUs
        const int qpb = (n4 + C2 - 1) / C2;      // <= 4096 by construction
        prod_kernel<<<C2, GBLK, (size_t)lds_prod, stream>>>(
            (const float4*)w, (const int4*)src, (const int4*)dst,
            normh, normh + N_NODES, (float4*)out,
            n4, E, qpb, NR, w, src, dst, out);
    }
}

// Round 15
// 68.425 us; speedup vs baseline: 1.2058x; 1.2058x over previous
//
#include <hip/hip_runtime.h>
#include <hip/hip_fp16.h>

// EdgeWeightNorm (norm='both'), EPS = 0.
// out[e] = outdeg[src[e]]^-0.5 * indeg[dst[e]]^-0.5 * w[e]
//
// Journal (final):
// R1/R2: global fp32 atomics go to the coherence point regardless of scope
//   (~20 G atomics/s, 32B write-through each) -> never use them.
// R3: multi-pass LDS histograms (u32 fixed-point, ds_add_u32).
// R4: 160KB LDS -> fewer passes. R5: pack outdeg(lo16)/indeg(hi16) in one
//   u32 -> 3 passes cover both degree sums; one reduce load serves both.
// R6/R7: random VMEM gathers pinned by per-CU outstanding-miss cap
//   (0.35 lines/cy/CU); ILP and NT hints null.
// R8: prod gathers from LDS-resident f16 norm slices (edges in registers).
// R9: XCD co-schedule swizzle: FETCH 112->37.5MB, time ~flat (latency-bound).
// R10: 1-deep hist pipeline: +1-2us only. R11: reg-staged dbuf prod spilled
//   (WRITE 120MB scratch) -> regressed. R12: KMAX=4 + 2 blocks/CU TLP prod
//   -> TOTAL 68.8us (best). R13/R14: 10-bit x3 packing branch regressed
//   (77/82us): reduce volume grew (separate src/dst sections) and hist's
//   cost is per-edge constant, not pass count. REVERTED to R12 config.

#define N_NODES 100000
#define TWO_N   (2 * N_NODES)
#define THREADS 1024
#define GBLK    1024
#define KMAX    4              // quads per thread in prod (4*1024*512 >= n4)
#define SCALE_F   512.0f       // 2^9
#define INV_SCALE 0.001953125f // 2^-9

// ---------------- degree histogram ----------------
// grid = P*C blocks. pass j covers nodes [j*bins,(j+1)*bins) for BOTH
// histograms (packed u16 halves); chunk c over edge quads.
// swz!=0 requires C%8==0: same-chunk triples co-resident on one XCD.
__global__ __launch_bounds__(THREADS, 4)
void hist_kernel(const float4* __restrict__ w4,
                 const int4* __restrict__ src4,
                 const int4* __restrict__ dst4,
                 const float* __restrict__ w,
                 const int* __restrict__ src,
                 const int* __restrict__ dst,
                 unsigned* __restrict__ parts,
                 int n4, int n_edges, int P, int C, int bins, int chunk4,
                 int swz)
{
    extern __shared__ unsigned lds[];
    int j, c;
    if (swz) {
        const int x = blockIdx.x & 7;
        const int r = blockIdx.x >> 3;
        j = r % P;
        c = x + 8 * (r / P);
    } else {
        j = blockIdx.x / C;
        c = blockIdx.x - j * C;
    }
    const int lo = j * bins;

    for (int k = threadIdx.x; k < bins; k += THREADS) lds[k] = 0;
    __syncthreads();

    const int beg = c * chunk4;
    const int end = min(n4, beg + chunk4);
    const int t   = threadIdx.x;

#define QUAD(wv, sv, dv)                                                      \
    do {                                                                      \
        unsigned v0 = (unsigned)((wv).x * SCALE_F + 0.5f);                    \
        unsigned v1 = (unsigned)((wv).y * SCALE_F + 0.5f);                    \
        unsigned v2 = (unsigned)((wv).z * SCALE_F + 0.5f);                    \
        unsigned v3 = (unsigned)((wv).w * SCALE_F + 0.5f);                    \
        int a0 = (sv).x - lo, a1 = (sv).y - lo, a2 = (sv).z - lo, a3 = (sv).w - lo; \
        int b0 = (dv).x - lo, b1 = (dv).y - lo, b2 = (dv).z - lo, b3 = (dv).w - lo; \
        if ((unsigned)a0 < (unsigned)bins) atomicAdd(&lds[a0], v0);           \
        if ((unsigned)a1 < (unsigned)bins) atomicAdd(&lds[a1], v1);           \
        if ((unsigned)a2 < (unsigned)bins) atomicAdd(&lds[a2], v2);           \
        if ((unsigned)a3 < (unsigned)bins) atomicAdd(&lds[a3], v3);           \
        if ((unsigned)b0 < (unsigned)bins) atomicAdd(&lds[b0], v0 << 16);     \
        if ((unsigned)b1 < (unsigned)bins) atomicAdd(&lds[b1], v1 << 16);     \
        if ((unsigned)b2 < (unsigned)bins) atomicAdd(&lds[b2], v2 << 16);     \
        if ((unsigned)b3 < (unsigned)bins) atomicAdd(&lds[b3], v3 << 16);     \
    } while (0)

    // 1-deep software pipeline over groups of 2 quads (6 vec4 loads/group).
    {
        const int total = end - beg;                          // uniform
        const int trips = (total + 2 * THREADS - 1) / (2 * THREADS);
        int i = beg + t;

        float4 wc0, wc1, wn0, wn1;
        int4   sc0, sc1, sn0, sn1, dc0, dc1, dn0, dn1;
        bool   pc0, pc1, pn0, pn1;

        pn0 = i < end;
        pn1 = (i + THREADS) < end;
        if (pn0) { wn0 = w4[i];           sn0 = src4[i];           dn0 = dst4[i]; }
        if (pn1) { wn1 = w4[i + THREADS]; sn1 = src4[i + THREADS]; dn1 = dst4[i + THREADS]; }

        for (int tr = 0; tr < trips; ++tr) {
            wc0 = wn0; sc0 = sn0; dc0 = dn0; pc0 = pn0;
            wc1 = wn1; sc1 = sn1; dc1 = dn1; pc1 = pn1;

            const int ni = i + 2 * THREADS;
            pn0 = (tr + 1 < trips) && (ni < end);
            pn1 = (tr + 1 < trips) && ((ni + THREADS) < end);
            if (pn0) { wn0 = w4[ni];           sn0 = src4[ni];           dn0 = dst4[ni]; }
            if (pn1) { wn1 = w4[ni + THREADS]; sn1 = src4[ni + THREADS]; dn1 = dst4[ni + THREADS]; }

            __builtin_amdgcn_sched_barrier(0);

            if (pc0) QUAD(wc0, sc0, dc0);
            if (pc1) QUAD(wc1, sc1, dc1);
            i = ni;
        }
    }
#undef QUAD

    if (c == C - 1 && threadIdx.x == 0) {        // tail edges (none for E=6.4M)
        for (int e = n4 * 4; e < n_edges; ++e) {
            unsigned v = (unsigned)(w[e] * SCALE_F + 0.5f);
            int a = src[e] - lo;
            int b = dst[e] - lo;
            if ((unsigned)a < (unsigned)bins) atomicAdd(&lds[a], v);
            if ((unsigned)b < (unsigned)bins) atomicAdd(&lds[b], v << 16);
        }
    }

    __syncthreads();
    unsigned* op = parts + (size_t)(j * C + c) * bins;
    for (int k = threadIdx.x; k < bins; k += THREADS)
        __builtin_nontemporal_store(lds[k], op + k);   // bulk dump
}

// ------------- reduce partials -> f16 norm tables (deg^-0.5) -------------
// One thread per node; each packed word serves BOTH tables (one load).
__global__ void reduce_rsqrt_kernel(const unsigned* __restrict__ parts,
                                    __half* __restrict__ normh,
                                    int P, int C, int bins)
{
    int i = blockIdx.x * blockDim.x + threadIdx.x;
    if (i >= N_NODES) return;
    int p = i / bins;
    int b = i - p * bins;
    const unsigned* base = parts + ((size_t)p * C) * bins + b;
    unsigned lo0 = 0, hi0 = 0, lo1 = 0, hi1 = 0, lo2 = 0, hi2 = 0, lo3 = 0, hi3 = 0;
    int c = 0;
    for (; c + 3 < C; c += 4) {
        unsigned v0 = base[(size_t)(c + 0) * bins];
        unsigned v1 = base[(size_t)(c + 1) * bins];
        unsigned v2 = base[(size_t)(c + 2) * bins];
        unsigned v3 = base[(size_t)(c + 3) * bins];
        lo0 += v0 & 0xFFFFu; hi0 += v0 >> 16;
        lo1 += v1 & 0xFFFFu; hi1 += v1 >> 16;
        lo2 += v2 & 0xFFFFu; hi2 += v2 >> 16;
        lo3 += v3 & 0xFFFFu; hi3 += v3 >> 16;
    }
    for (; c < C; ++c) {
        unsigned v = base[(size_t)c * bins];
        lo0 += v & 0xFFFFu; hi0 += v >> 16;
    }
    unsigned lo_s = lo0 + lo1 + lo2 + lo3;
    unsigned hi_s = hi0 + hi1 + hi2 + hi3;
    // deg==0 -> inf matches 0**-0.5 (never gathered: an edge implies deg>0)
    normh[i]           = __float2half(1.0f / sqrtf((float)lo_s * INV_SCALE));
    normh[N_NODES + i] = __float2half(1.0f / sqrtf((float)hi_s * INV_SCALE));
}

// ---------------- fallback path (tiny ws): device atomics ----------------
__global__ void degree_atomic_kernel(const float* __restrict__ w,
                                     const int* __restrict__ src,
                                     const int* __restrict__ dst,
                                     float* __restrict__ deg,
                                     int n_edges)
{
    int i = blockIdx.x * blockDim.x + threadIdx.x;
    int stride = gridDim.x * blockDim.x;
    for (; i < n_edges; i += stride) {
        float wi = w[i];
        atomicAdd(&deg[src[i]], wi);
        atomicAdd(&deg[N_NODES + dst[i]], wi);
    }
}

__global__ void rsqrt_half_kernel(const float* __restrict__ deg,
                                  __half* __restrict__ normh, int n)
{
    int i = blockIdx.x * blockDim.x + threadIdx.x;
    if (i < n) normh[i] = __float2half(1.0f / sqrtf(deg[i]));
}

// ------- output pass: edges in regs (KMAX=4 -> no spill); single 80KB
// interleaved slice (srcn|dstn, NR nodes); 2 blocks/CU co-resident so one
// block's fill overlaps the other's gather (TLP, not staging regs). -------
__global__ __launch_bounds__(GBLK, 8)
void prod_kernel(const float4* __restrict__ w4,
                 const int4* __restrict__ src4,
                 const int4* __restrict__ dst4,
                 const __half* __restrict__ srcn_h,
                 const __half* __restrict__ dstn_h,
                 float4* __restrict__ out4,
                 int n4, int n_edges, int qpb, int NR,
                 const float* __restrict__ w,
                 const int* __restrict__ src,
                 const int* __restrict__ dst,
                 float* __restrict__ out)
{
    extern __shared__ __half lh[];     // [2*NR]: srcn slice | dstn slice
    const int q0   = blockIdx.x * qpb;
    const int qend = min(n4, q0 + qpb);
    const int t    = threadIdx.x;
    const int passes  = (N_NODES + NR - 1) / NR;
    const int half_u4 = NR >> 3;       // uint4 per table slice
    const int tot_u4  = NR >> 2;       // uint4 per (both-tables) slice

    float4 pr[KMAX];
    int4   sv[KMAX], dv[KMAX];
    bool   val[KMAX];
#pragma unroll
    for (int k = 0; k < KMAX; ++k) {
        const int q = q0 + k * GBLK + t;
        val[k] = q < qend;
        if (val[k]) {
            pr[k] = w4[q];             // product accumulator starts at w
            sv[k] = src4[q];
            dv[k] = dst4[q];
        }
    }

    for (int p = 0; p < passes; ++p) {
        if (p > 0) __syncthreads();            // prev gathers done before overwrite
        {
            const int base_ = p * NR;
            const uint4* gs = (const uint4*)(srcn_h + base_);
            const uint4* gd = (const uint4*)(dstn_h + base_);
            uint4* lb = (uint4*)lh;
            for (int idx = t; idx < tot_u4; idx += GBLK)
                lb[idx] = (idx < half_u4) ? gs[idx] : gd[idx - half_u4];
        }
        __syncthreads();

        const int lo = p * NR;
        const unsigned lenU = (unsigned)min(NR, N_NODES - lo);
        const __half* ls  = lh;
        const __half* ldt = lh + NR;
#pragma unroll
        for (int k = 0; k < KMAX; ++k) {
            if (!val[k]) continue;
            unsigned a;
            a = (unsigned)(sv[k].x - lo); if (a < lenU) pr[k].x *= __half2float(ls[a]);
            a = (unsigned)(sv[k].y - lo); if (a < lenU) pr[k].y *= __half2float(ls[a]);
            a = (unsigned)(sv[k].z - lo); if (a < lenU) pr[k].z *= __half2float(ls[a]);
            a = (unsigned)(sv[k].w - lo); if (a < lenU) pr[k].w *= __half2float(ls[a]);
            a = (unsigned)(dv[k].x - lo); if (a < lenU) pr[k].x *= __half2float(ldt[a]);
            a = (unsigned)(dv[k].y - lo); if (a < lenU) pr[k].y *= __half2float(ldt[a]);
            a = (unsigned)(dv[k].z - lo); if (a < lenU) pr[k].z *= __half2float(ldt[a]);
            a = (unsigned)(dv[k].w - lo); if (a < lenU) pr[k].w *= __half2float(ldt[a]);
        }
    }

#pragma unroll
    for (int k = 0; k < KMAX; ++k) {
        const int q = q0 + k * GBLK + t;
        if (val[k]) out4[q] = pr[k];
    }

    if (blockIdx.x == 0 && t == 0) {   // tail edges (none for E=6.4M)
        for (int e = n4 * 4; e < n_edges; ++e)
            out[e] = __half2float(srcn_h[src[e]]) * __half2float(dstn_h[dst[e]]) * w[e];
    }
}

extern "C" void kernel_launch(void* const* d_in, const int* in_sizes, int n_in,
                              void* d_out, int out_size, void* d_ws, size_t ws_size,
                              hipStream_t stream)
{
    const float* w   = (const float*)d_in[0];
    const int*   src = (const int*)d_in[1];
    const int*   dst = (const int*)d_in[2];
    const int E  = in_sizes[0];
    const int n4 = E >> 2;
    float* out = (float*)d_out;

    // ws layout: [0, 1MB) f16 norm tables (srcn | dstn; slack for OOB-safe
    // vectorized slice fills); [1MB, ...) scratch
    __half* normh = (__half*)d_ws;
    char* scratch = (char*)d_ws + (1 << 20);
    unsigned* parts = (unsigned*)scratch;
    float* degf = (float*)scratch;               // fallback f32 degrees
    size_t avail_u = (ws_size > (1u << 20)) ? (ws_size - (1 << 20)) / 4 : 0;

    // hist wants max LDS (fewest passes): 160KB -> 128 -> 80 -> 64KB.
    const int cands[3] = {163840, 131072, 81920};
    int lds_hist = 65536;
    for (int tC = 0; tC < 3; ++tC)
        if (hipFuncSetAttribute((const void*)hist_kernel,
                                hipFuncAttributeMaxDynamicSharedMemorySize,
                                cands[tC]) == hipSuccess) { lds_hist = cands[tC]; break; }
    // prod wants 80KB (2 blocks/CU co-residency); fallback 64KB.
    int lds_prod = 65536;
    if (hipFuncSetAttribute((const void*)prod_kernel,
                            hipFuncAttributeMaxDynamicSharedMemorySize,
                            81920) == hipSuccess)
        lds_prod = 81920;

    const int bins = lds_hist / 4;               // u32 packed degree counters
    const int P = (N_NODES + bins - 1) / bins;   // 3 at 160KB

    const int blk_per_cu = 163840 / lds_hist;
    int C = (256 * blk_per_cu) / P;              // 85 at 160KB
    const size_t per_chunk_u = (size_t)P * (size_t)bins;
    if (avail_u < per_chunk_u) C = 0;
    else {
        int cmax = (int)(avail_u / per_chunk_u);
        if (C > cmax) C = cmax;
    }

    // XCD co-scheduling swizzle needs C % 8 == 0 (C=80 at 160KB LDS).
    int swz = 0;
    if (C >= 8) { C &= ~7; swz = 1; }

    if (C >= 1) {
        const int chunk4 = (n4 + C - 1) / C;
        hist_kernel<<<P * C, THREADS, (size_t)lds_hist, stream>>>(
            (const float4*)w, (const int4*)src, (const int4*)dst,
            w, src, dst, parts, n4, E, P, C, bins, chunk4, swz);
        reduce_rsqrt_kernel<<<(N_NODES + 255) / 256, 256, 0, stream>>>(
            parts, normh, P, C, bins);
    } else {
        hipMemsetAsync(degf, 0, (size_t)TWO_N * sizeof(float), stream);
        degree_atomic_kernel<<<2048, 256, 0, stream>>>(w, src, dst, degf, E);
        rsqrt_half_kernel<<<(TWO_N + 255) / 256, 256, 0, stream>>>(degf, normh, TWO_N);
    }

    {
        // NR nodes per slice; LDS = 2 tables x NR x 2B = 4*NR bytes.
        const int NR = lds_prod / 4;             // 20480 at 80KB
        const int maxq = KMAX * GBLK;            // 4096 quads/block capacity
        int C2 = (n4 + maxq - 1) / maxq;
        if (C2 < 512) C2 = 512;                  // 2 blocks/CU on all CUs
        const int qpb = (n4 + C2 - 1) / C2;      // <= 4096 by construction
        prod_kernel<<<C2, GBLK, (size_t)lds_prod, stream>>>(
            (const float4*)w, (const int4*)src, (const int4*)dst,
            normh, normh + N_NODES, (float4*)out,
            n4, E, qpb, NR, w, src, dst, out);
    }
}